// Round 12
// baseline (145.240 us; speedup 1.0000x reference)
//
#include <hip/hip_runtime.h>

typedef __attribute__((ext_vector_type(8))) short short8;
typedef __attribute__((ext_vector_type(4))) float f32x4;

constexpr int NTOK = 65536;
constexpr int DIM  = 128;
constexpr int NK   = 1024;

__device__ __forceinline__ unsigned short f2bf(float f) {
  unsigned int u = __float_as_uint(f);
  unsigned int r = u + 0x7fffu + ((u >> 16) & 1u);
  return (unsigned short)(r >> 16);
}
__device__ __forceinline__ float bf2f(unsigned short h) {
  return __uint_as_float(((unsigned int)h) << 16);
}

// ---- prep: emb -> frag-major bf16 hi|lo image for direct reg loads ----
// frag addr = chunk*16384 + kk*4096 + hilo*2048 + n*1024 + lane*16
// + embT + f64 |e|^2 + scaled-key e2s; zeroes nflag.
__global__ void bprep_k(const float* __restrict__ emb, char* __restrict__ bp,
                        float* __restrict__ embT, float* __restrict__ e2s,
                        double* __restrict__ en2d, int* __restrict__ nflag) {
  int i = blockIdx.x * 256 + threadIdx.x;   // 0..16383
  if (i == 0) *nflag = 0;
  int c = i >> 4;          // code
  int g = i & 15;          // dim group (8 dims)
  float4 v0 = *(const float4*)&emb[c * 128 + g * 8];
  float4 v1 = *(const float4*)&emb[c * 128 + g * 8 + 4];
  float vf[8] = {v0.x, v0.y, v0.z, v0.w, v1.x, v1.y, v1.z, v1.w};
  unsigned short hh[8], ll[8];
  double pacc = 0.0;
#pragma unroll
  for (int j = 0; j < 8; j++) {
    hh[j] = f2bf(vf[j]);
    ll[j] = f2bf(vf[j] - bf2f(hh[j]));
    embT[(g * 8 + j) * NK + c] = vf[j];
    pacc = fma((double)vf[j], (double)vf[j], pacc);
  }
  uint4 hv, lv;
  hv.x = (unsigned)hh[0] | ((unsigned)hh[1] << 16); hv.y = (unsigned)hh[2] | ((unsigned)hh[3] << 16);
  hv.z = (unsigned)hh[4] | ((unsigned)hh[5] << 16); hv.w = (unsigned)hh[6] | ((unsigned)hh[7] << 16);
  lv.x = (unsigned)ll[0] | ((unsigned)ll[1] << 16); lv.y = (unsigned)ll[2] | ((unsigned)ll[3] << 16);
  lv.z = (unsigned)ll[4] | ((unsigned)ll[5] << 16); lv.w = (unsigned)ll[6] | ((unsigned)ll[7] << 16);
  int chunk = c >> 5, n = (c >> 4) & 1, cl = c & 15;
  int kk = g >> 2, l4 = g & 3;
  char* cb = bp + chunk * 16384 + kk * 4096 + n * 1024 + (l4 * 16 + cl) * 16;
  *(uint4*)cb = hv;
  *(uint4*)(cb + 2048) = lv;
#pragma unroll
  for (int mask = 1; mask < 16; mask <<= 1) pacc += __shfl_xor(pacc, mask);
  if (g == 0) {
    en2d[c] = pacc;
    e2s[c] = (float)(pacc * 134217728.0 + 1073741824.0);  // e2*2^27 + 2^30
  }
}

// ---- main: MFMA bf16-split distance + u32-key argmin + fused out_q/loss ----
// 1024 blocks x 128 thr (2 waves). No LDS staging, no barriers in main loop.
// Two 4-slot register banks: 2-chunk prefetch lookahead (~7 phases).
__global__ __launch_bounds__(128, 2)
void argmin_k(const float* __restrict__ x, const char* __restrict__ bp,
              const float* __restrict__ e2s, const float* __restrict__ emb,
              int* __restrict__ idx_arr, float* __restrict__ out_idx,
              int* __restrict__ nflag, int* __restrict__ flags,
              float* __restrict__ partial, float* __restrict__ out_q) {
  __shared__ float wsum[2];
  const int t    = threadIdx.x;
  const int lane = t & 63;
  const int w    = t >> 6;              // 0..1
  const int l15  = lane & 15;
  const int lo4  = lane >> 4;
  const int rbase = blockIdx.x * 64;
  const int lb16 = lane * 16;

  short8 FA[4][4], FB[4][4];   // [kk][frag: hi_n0, hi_n1, lo_n0, lo_n1]

#define LOADG(DST, C, KK)                                                      \
  {                                                                            \
    const char* _b = bp + ((C) * 16384 + (KK) * 4096) + lb16;                  \
    DST[0] = *(const short8*)_b;                                               \
    DST[1] = *(const short8*)(_b + 1024);                                      \
    DST[2] = *(const short8*)(_b + 2048);                                      \
    DST[3] = *(const short8*)(_b + 3072);                                      \
  }

  // prolog: chunks 0 and 1 fully in flight
#pragma unroll
  for (int kk = 0; kk < 4; kk++) LOADG(FA[kk], 0, kk)
#pragma unroll
  for (int kk = 0; kk < 4; kk++) LOADG(FB[kk], 1, kk)

  // A-frags (m=2) + per-row |x|^2
  short8 ah[2][4], al[2][4];
  float xn2[2] = {0.f, 0.f};
#pragma unroll
  for (int m = 0; m < 2; m++)
#pragma unroll
    for (int kk = 0; kk < 4; kk++) {
      const float* xp = &x[(rbase + w * 32 + m * 16 + l15) * 128 + kk * 32 + lo4 * 8];
      float4 v0 = *(const float4*)xp;
      float4 v1 = *(const float4*)(xp + 4);
      float vf[8] = {v0.x, v0.y, v0.z, v0.w, v1.x, v1.y, v1.z, v1.w};
      unsigned short hh[8], ll[8];
#pragma unroll
      for (int j = 0; j < 8; j++) {
        hh[j] = f2bf(vf[j]);
        ll[j] = f2bf(vf[j] - bf2f(hh[j]));
        xn2[m] = fmaf(vf[j], vf[j], xn2[m]);
      }
      unsigned hu[4] = {(unsigned)hh[0] | ((unsigned)hh[1] << 16), (unsigned)hh[2] | ((unsigned)hh[3] << 16),
                        (unsigned)hh[4] | ((unsigned)hh[5] << 16), (unsigned)hh[6] | ((unsigned)hh[7] << 16)};
      unsigned lu[4] = {(unsigned)ll[0] | ((unsigned)ll[1] << 16), (unsigned)ll[2] | ((unsigned)ll[3] << 16),
                        (unsigned)ll[4] | ((unsigned)ll[5] << 16), (unsigned)ll[6] | ((unsigned)ll[7] << 16)};
      ah[m][kk] = *(short8*)hu;
      al[m][kk] = *(short8*)lu;
    }
  // complete |x|^2 across the 4 lo4 lanes (dims partition)
#pragma unroll
  for (int m = 0; m < 2; m++) {
    xn2[m] += __shfl_xor(xn2[m], 16);
    xn2[m] += __shfl_xor(xn2[m], 32);
  }

  unsigned bv[2][4], b2[2][4];
#pragma unroll
  for (int m = 0; m < 2; m++)
#pragma unroll
    for (int r = 0; r < 4; r++) { bv[m][r] = 0xFFFFFFFFu; b2[m][r] = 0xFFFFFFFFu; }

#define MFMA_PHASE(BANK, KK)                                                   \
  {                                                                            \
    acc[0][0] = __builtin_amdgcn_mfma_f32_16x16x32_bf16(ah[0][KK], BANK[KK][0], acc[0][0], 0, 0, 0); \
    acc[1][0] = __builtin_amdgcn_mfma_f32_16x16x32_bf16(ah[1][KK], BANK[KK][0], acc[1][0], 0, 0, 0); \
    acc[0][1] = __builtin_amdgcn_mfma_f32_16x16x32_bf16(ah[0][KK], BANK[KK][1], acc[0][1], 0, 0, 0); \
    acc[1][1] = __builtin_amdgcn_mfma_f32_16x16x32_bf16(ah[1][KK], BANK[KK][1], acc[1][1], 0, 0, 0); \
    acc[0][0] = __builtin_amdgcn_mfma_f32_16x16x32_bf16(ah[0][KK], BANK[KK][2], acc[0][0], 0, 0, 0); \
    acc[1][0] = __builtin_amdgcn_mfma_f32_16x16x32_bf16(ah[1][KK], BANK[KK][2], acc[1][0], 0, 0, 0); \
    acc[0][1] = __builtin_amdgcn_mfma_f32_16x16x32_bf16(ah[0][KK], BANK[KK][3], acc[0][1], 0, 0, 0); \
    acc[1][1] = __builtin_amdgcn_mfma_f32_16x16x32_bf16(ah[1][KK], BANK[KK][3], acc[1][1], 0, 0, 0); \
    acc[0][0] = __builtin_amdgcn_mfma_f32_16x16x32_bf16(al[0][KK], BANK[KK][0], acc[0][0], 0, 0, 0); \
    acc[1][0] = __builtin_amdgcn_mfma_f32_16x16x32_bf16(al[1][KK], BANK[KK][0], acc[1][0], 0, 0, 0); \
    acc[0][1] = __builtin_amdgcn_mfma_f32_16x16x32_bf16(al[0][KK], BANK[KK][1], acc[0][1], 0, 0, 0); \
    acc[1][1] = __builtin_amdgcn_mfma_f32_16x16x32_bf16(al[1][KK], BANK[KK][1], acc[1][1], 0, 0, 0); \
  }

#define KEY_EPI(C)                                                             \
  {                                                                            \
    _Pragma("unroll")                                                          \
    for (int n = 0; n < 2; n++) {                                              \
      unsigned col = (unsigned)((C) * 32 + n * 16 + l15);                      \
      float e2v = n ? e2b : e2a;                                               \
      _Pragma("unroll")                                                        \
      for (int m = 0; m < 2; m++)                                              \
        _Pragma("unroll")                                                      \
        for (int r = 0; r < 4; r++) {                                          \
          float ks = fmaf(acc[m][n][r], -268435456.0f, e2v);                   \
          unsigned key = ((unsigned)ks & 0xFFFFFC00u) | col;                   \
          unsigned old = bv[m][r];                                             \
          bv[m][r] = min(old, key);                                            \
          b2[m][r] = min(b2[m][r], max(old, key));                             \
        }                                                                      \
    }                                                                          \
  }

  for (int c = 0; c < 32; c += 2) {
    // ---- chunk c from bank A; refill A with chunk c+2 as slots free up
    {
      float e2a = e2s[c * 32 + l15];
      float e2b = e2s[c * 32 + 16 + l15];
      f32x4 acc[2][2];
#pragma unroll
      for (int m = 0; m < 2; m++)
#pragma unroll
        for (int n = 0; n < 2; n++) acc[m][n] = (f32x4)(0.0f);
#pragma unroll
      for (int kk = 0; kk < 4; kk++) {
        MFMA_PHASE(FA, kk)
        if (c + 2 < 32) LOADG(FA[kk], c + 2, kk)
      }
      KEY_EPI(c)
    }
    // ---- chunk c+1 from bank B; refill B with chunk c+3
    {
      float e2a = e2s[(c + 1) * 32 + l15];
      float e2b = e2s[(c + 1) * 32 + 16 + l15];
      f32x4 acc[2][2];
#pragma unroll
      for (int m = 0; m < 2; m++)
#pragma unroll
        for (int n = 0; n < 2; n++) acc[m][n] = (f32x4)(0.0f);
#pragma unroll
      for (int kk = 0; kk < 4; kk++) {
        MFMA_PHASE(FB, kk)
        if (c + 3 < 32) LOADG(FB[kk], c + 3, kk)
      }
      KEY_EPI(c + 1)
    }
  }
#undef LOADG
#undef MFMA_PHASE
#undef KEY_EPI

  // 16-lane reduce (u32 min keeps tie-break = smaller col); v uniform in group
#pragma unroll
  for (int m = 0; m < 2; m++)
#pragma unroll
    for (int r = 0; r < 4; r++) {
      unsigned v = bv[m][r], v2 = b2[m][r];
      for (int mask = 1; mask < 16; mask <<= 1) {
        unsigned ov = __shfl_xor(v, mask);
        unsigned o2 = __shfl_xor(v2, mask);
        v2 = min(min(v2, o2), max(v, ov));
        v  = min(v, ov);
      }
      bv[m][r] = v; b2[m][r] = v2;
      if (l15 == 0) {
        int row = rbase + w * 32 + m * 16 + lo4 * 4 + r;
        int ii = (int)(v & 1023u);
        idx_arr[row] = ii;
        out_idx[row] = (float)ii;
        if ((v2 >> 10) - (v >> 10) < 39u) {   // gap < 3e-4 in score units
          int p = atomicAdd(nflag, 1); flags[p] = row;
        }
      }
    }

  // fused: gather emb[ii] -> out_q rows; loss partial from key score + |x|^2
  float lsum = 0.f;
#pragma unroll
  for (int m = 0; m < 2; m++)
#pragma unroll
    for (int r = 0; r < 4; r++)
#pragma unroll
      for (int q = 0; q < 4; q++) {
        unsigned vv = __shfl(bv[m][r], q * 16);
        int ii = (int)(vv & 1023u);
        int row = rbase + w * 32 + m * 16 + q * 4 + r;
        float2 ev = *(const float2*)&emb[ii * 128 + lane * 2];
        *(float2*)&out_q[row * 128 + lane * 2] = ev;
        float sc = ((float)(vv & 0xFFFFFC00u) - 1073741824.0f) * 7.450580597e-9f;
        float xr = __shfl(xn2[m], q * 4 + r);
        lsum += sc + xr;     // uniform across lanes
      }
  if (lane == 0) wsum[w] = lsum;
  __syncthreads();
  if (t == 0) partial[blockIdx.x] = wsum[0] + wsum[1];
}

// ---- exact f64 recompute for near-tie rows; patches idx + out_q ----
__global__ __launch_bounds__(256)
void fb_k(const float* __restrict__ x, const float* __restrict__ embT,
          const float* __restrict__ emb, const double* __restrict__ en2d,
          const int* __restrict__ nflag, const int* __restrict__ flags,
          int* __restrict__ idx_arr, float* __restrict__ out_idx,
          float* __restrict__ out_q) {
  int n = *nflag;
  __shared__ double xsh[DIM];
  __shared__ double sv[256];
  __shared__ int    si[256];
  int t = threadIdx.x;
  for (int f = blockIdx.x; f < n; f += gridDim.x) {
    int row = flags[f];
    int old = idx_arr[row];
    __syncthreads();
    if (t < DIM) xsh[t] = (double)x[row * DIM + t];
    __syncthreads();
    double xe0 = 0.0, xe1 = 0.0, xe2 = 0.0, xe3 = 0.0;
#pragma unroll 4
    for (int d = 0; d < DIM; d++) {
      float4 v = *(const float4*)&embT[d * NK + t * 4];
      double xd = xsh[d];
      xe0 = fma((double)v.x, xd, xe0);
      xe1 = fma((double)v.y, xd, xe1);
      xe2 = fma((double)v.z, xd, xe2);
      xe3 = fma((double)v.w, xd, xe3);
    }
    double s0 = en2d[t * 4 + 0] - 2.0 * xe0;
    double s1 = en2d[t * 4 + 1] - 2.0 * xe1;
    double s2 = en2d[t * 4 + 2] - 2.0 * xe2;
    double s3 = en2d[t * 4 + 3] - 2.0 * xe3;
    double bvv = s0; int bii = t * 4;
    if (s1 < bvv) { bvv = s1; bii = t * 4 + 1; }
    if (s2 < bvv) { bvv = s2; bii = t * 4 + 2; }
    if (s3 < bvv) { bvv = s3; bii = t * 4 + 3; }
    sv[t] = bvv; si[t] = bii;
    __syncthreads();
    for (int sh = 128; sh > 0; sh >>= 1) {
      if (t < sh) {
        double ov = sv[t + sh]; int oi = si[t + sh];
        if (ov < sv[t] || (ov == sv[t] && oi < si[t])) { sv[t] = ov; si[t] = oi; }
      }
      __syncthreads();
    }
    int nw = si[0];
    if (nw != old) {
      if (t == 0) { idx_arr[row] = nw; out_idx[row] = (float)nw; }
      if (t < DIM) out_q[row * DIM + t] = emb[nw * DIM + t];
    }
  }
}

// ---- per-block histogram (LDS bins, plain stores) ----
__global__ void histb_k(const int* __restrict__ idx, unsigned* __restrict__ bcount) {
  __shared__ unsigned bins[NK];
  int t = threadIdx.x;
  for (int b = t; b < NK; b += 256) bins[b] = 0u;
  __syncthreads();
#pragma unroll
  for (int j = 0; j < 4; j++)
    atomicAdd(&bins[idx[blockIdx.x * 1024 + j * 256 + t]], 1u);
  __syncthreads();
  for (int b = t; b < NK; b += 256) bcount[blockIdx.x * NK + b] = bins[b];
}

// ---- totals + scan + per-block starts + ncs/csk ----
__global__ void scan_k(unsigned* __restrict__ bcount, unsigned* __restrict__ icounts,
                       unsigned* __restrict__ offsets, const float* __restrict__ cs,
                       float* __restrict__ out_ncs, float* __restrict__ csk) {
  __shared__ unsigned sc[NK];
  __shared__ float sf[NK];
  int t = threadIdx.x;
  unsigned tot = 0;
#pragma unroll 8
  for (int b = 0; b < 64; b++) tot += bcount[b * NK + t];
  icounts[t] = tot;
  sc[t] = tot;
  __syncthreads();
  for (int off = 1; off < NK; off <<= 1) {
    unsigned v = (t >= off) ? sc[t - off] : 0u;
    __syncthreads();
    sc[t] += v;
    __syncthreads();
  }
  unsigned excl = sc[t] - tot;
  offsets[t] = excl;
  unsigned run = excl;
#pragma unroll 8
  for (int b = 0; b < 64; b++) {
    unsigned c = bcount[b * NK + t];
    bcount[b * NK + t] = run;          // becomes per-block start
    run += c;
  }
  float c0 = cs[t];
  float ncs = c0 * 0.99f + 0.01f * (float)tot;
  out_ncs[t] = ncs;
  sf[t] = c0;
  __syncthreads();
  for (int s = 512; s > 0; s >>= 1) {
    if (t < s) sf[t] += sf[t + s];
    __syncthreads();
  }
  float n = 0.99f * sf[0] + 655.36f;   // sum(ncs) = 0.99*sum(cs) + 0.01*65536
  csk[t] = (ncs + 1e-5f) / (n + 1024.0f * 1e-5f) * n;
}

// ---- scatter row ids (LDS cursors; no global atomics) ----
__global__ void scatter_k(const int* __restrict__ idx, const unsigned* __restrict__ bstart,
                          int* __restrict__ order) {
  __shared__ unsigned cur[NK];
  int t = threadIdx.x;
  for (int b = t; b < NK; b += 256) cur[b] = bstart[blockIdx.x * NK + b];
  __syncthreads();
#pragma unroll
  for (int j = 0; j < 4; j++) {
    int r = blockIdx.x * 1024 + j * 256 + t;
    unsigned p = atomicAdd(&cur[idx[r]], 1u);
    order[p] = r;
  }
}

// ---- gather: dw_embed segment sums only ----
__global__ __launch_bounds__(512)
void fgather_k(const float* __restrict__ x, const unsigned* __restrict__ offsets,
               const unsigned* __restrict__ icounts, const int* __restrict__ order,
               float* __restrict__ dwsum) {
  int k = blockIdx.x, t = threadIdx.x;
  int d = t & 127, h = t >> 7;   // h = 0..3
  unsigned s = offsets[k], cnt = icounts[k];
  float acc = 0.f;
  for (unsigned j = h; j < cnt; j += 4) {
    int row = order[s + j];
    acc += x[row * DIM + d];
  }
  __shared__ float sa[512];
  sa[t] = acc;
  __syncthreads();
  if (t < 128) dwsum[k * DIM + t] = sa[t] + sa[t + 128] + sa[t + 256] + sa[t + 384];
}

// ---- embed_avg EMA + new embedding; block 0 reduces loss ----
__global__ void emb_k(const float* __restrict__ embed_avg, const float* __restrict__ dwsum,
                      const float* __restrict__ csk, const float* __restrict__ partial,
                      float* __restrict__ out_nemb, float* __restrict__ out_nea,
                      float* __restrict__ out_loss) {
  if (blockIdx.x == 0) {
    __shared__ float red[256];
    int t = threadIdx.x;
    red[t] = partial[t] + partial[t + 256] + partial[t + 512] + partial[t + 768];
    __syncthreads();
    for (int sh = 128; sh > 0; sh >>= 1) {
      if (t < sh) red[t] += red[t + sh];
      __syncthreads();
    }
    if (t == 0) out_loss[0] = 2.0f * red[0] / 8388608.0f;
    return;
  }
  int i = (blockIdx.x - 1) * 256 + threadIdx.x;
  float na = embed_avg[i] * 0.99f + 0.01f * dwsum[i];
  out_nea[i] = na;
  out_nemb[i] = na / csk[i >> 7];
}

extern "C" void kernel_launch(void* const* d_in, const int* in_sizes, int n_in,
                              void* d_out, int out_size, void* d_ws, size_t ws_size,
                              hipStream_t stream) {
  const float* x   = (const float*)d_in[0];
  const float* emb = (const float*)d_in[1];
  const float* cs  = (const float*)d_in[2];
  const float* ea  = (const float*)d_in[3];

  float* out      = (float*)d_out;
  float* out_q    = out;                      // [65536,128]
  float* out_loss = out + 8388608;            // scalar
  float* out_idx  = out + 8388609;            // [65536]
  float* out_nemb = out + 8454145;            // [1024,128]
  float* out_ncs  = out + 8585217;            // [1024]
  float* out_nea  = out + 8586241;            // [1024,128]

  float* W        = (float*)d_ws;
  float* e2s      = W;                              // [0,1024)
  double* en2d    = (double*)(W + 1024);            // [1024,3072)
  char*  bpack    = (char*)(W + 3072);              // [3072,134144) 512KB image
  float* dwsum    = W + 3072;                       // aliases bpack (dead after argmin)
  float* embT     = W + 134144;                     // [134144,265216) (dead after fb)
  unsigned* bcount = (unsigned*)(W + 134144);       // aliases embT lower (after fb)
  int*   order    = (int*)(W + 199680);             // aliases embT upper (after fb)
  float* partial  = W + 265216;                     // 1024
  unsigned* icounts = (unsigned*)(W + 266240);      // 1024
  unsigned* offsets = (unsigned*)(W + 267264);      // 1024
  float* csk      = W + 268288;                     // 1024
  int*   nflag    = (int*)(W + 269312);             // 1 (+pad)
  int*   flags    = (int*)(W + 269328);             // 65536
  int*   idx_arr  = (int*)(W + 334864);             // 65536

  bprep_k<<<64, 256, 0, stream>>>(emb, bpack, embT, e2s, en2d, nflag);
  argmin_k<<<1024, 128, 0, stream>>>(x, bpack, e2s, emb, idx_arr, out_idx, nflag,
                                     flags, partial, out_q);
  fb_k<<<1024, 256, 0, stream>>>(x, embT, emb, en2d, nflag, flags, idx_arr, out_idx, out_q);
  histb_k<<<64, 256, 0, stream>>>(idx_arr, bcount);
  scan_k<<<1, 1024, 0, stream>>>(bcount, icounts, offsets, cs, out_ncs, csk);
  scatter_k<<<64, 256, 0, stream>>>(idx_arr, bcount, order);
  fgather_k<<<1024, 512, 0, stream>>>(x, offsets, icounts, order, dwsum);
  emb_k<<<513, 256, 0, stream>>>(ea, dwsum, csk, partial, out_nemb, out_nea, out_loss);
}

// Round 13
// 117.692 us; speedup vs baseline: 1.2341x; 1.2341x over previous
//
#include <hip/hip_runtime.h>

typedef __attribute__((ext_vector_type(8))) _Float16 half8;
typedef __attribute__((ext_vector_type(4))) float f32x4;

constexpr int NTOK = 65536;
constexpr int DIM  = 128;
constexpr int NK   = 1024;

// ---- prep: emb -> frag-major fp16 image for direct reg loads ----
// frag addr = chunk*8192 + kk*2048 + n*1024 + (lo4*16 + cl)*16
// (code = chunk*32 + n*16 + cl; dims kk*32 + lo4*8 .. +8)
// + embT + f64 |e|^2 + scaled-key e2s; zeroes nflag.
__global__ void bprep_k(const float* __restrict__ emb, char* __restrict__ bp,
                        float* __restrict__ embT, float* __restrict__ e2s,
                        double* __restrict__ en2d, int* __restrict__ nflag) {
  int i = blockIdx.x * 256 + threadIdx.x;   // 0..16383
  if (i == 0) *nflag = 0;
  int c = i >> 4;          // code
  int g = i & 15;          // dim group (8 dims)
  float4 v0 = *(const float4*)&emb[c * 128 + g * 8];
  float4 v1 = *(const float4*)&emb[c * 128 + g * 8 + 4];
  float vf[8] = {v0.x, v0.y, v0.z, v0.w, v1.x, v1.y, v1.z, v1.w};
  half8 hv;
  double pacc = 0.0;
#pragma unroll
  for (int j = 0; j < 8; j++) {
    hv[j] = (_Float16)vf[j];
    embT[(g * 8 + j) * NK + c] = vf[j];
    pacc = fma((double)vf[j], (double)vf[j], pacc);
  }
  int chunk = c >> 5, n = (c >> 4) & 1, cl = c & 15;
  int kk = g >> 2, lo4 = g & 3;
  *(half8*)(bp + chunk * 8192 + kk * 2048 + n * 1024 + (lo4 * 16 + cl) * 16) = hv;
#pragma unroll
  for (int mask = 1; mask < 16; mask <<= 1) pacc += __shfl_xor(pacc, mask);
  if (g == 0) {
    en2d[c] = pacc;
    e2s[c] = (float)(pacc * 134217728.0 + 1073741824.0);  // e2*2^27 + 2^30
  }
}

// ---- main: fp16 MFMA distance + u32-key argmin ----
// 1024 blocks x 128 thr (2 waves). No LDS, no barriers: B-frags streamed
// global(L2)->reg via dual 4x2 register banks (2-chunk / 8-phase lookahead).
__global__ __launch_bounds__(128, 2)
void argmin_k(const float* __restrict__ x, const char* __restrict__ bp,
              const float* __restrict__ e2s, int* __restrict__ idx_arr,
              float* __restrict__ out_idx, int* __restrict__ nflag,
              int* __restrict__ flags) {
  const int t    = threadIdx.x;
  const int lane = t & 63;
  const int w    = t >> 6;              // 0..1
  const int l15  = lane & 15;
  const int lo4  = lane >> 4;
  const int rbase = blockIdx.x * 64;
  const int lb16 = lane * 16;

  half8 FA[4][2], FB[4][2];   // [kk][n]

#define LOADG(DST, C, KK)                                                      \
  {                                                                            \
    const char* _b = bp + ((C) * 8192 + (KK) * 2048) + lb16;                   \
    DST[0] = *(const half8*)_b;                                                \
    DST[1] = *(const half8*)(_b + 1024);                                       \
  }

  // prolog: chunks 0 and 1 fully in flight
#pragma unroll
  for (int kk = 0; kk < 4; kk++) LOADG(FA[kk], 0, kk)
#pragma unroll
  for (int kk = 0; kk < 4; kk++) LOADG(FB[kk], 1, kk)

  // A-frags (m=2): global -> regs, fp16 convert
  half8 ah[2][4];
#pragma unroll
  for (int m = 0; m < 2; m++)
#pragma unroll
    for (int kk = 0; kk < 4; kk++) {
      const float* xp = &x[(rbase + w * 32 + m * 16 + l15) * 128 + kk * 32 + lo4 * 8];
      float4 v0 = *(const float4*)xp;
      float4 v1 = *(const float4*)(xp + 4);
      float vf[8] = {v0.x, v0.y, v0.z, v0.w, v1.x, v1.y, v1.z, v1.w};
      half8 av;
#pragma unroll
      for (int j = 0; j < 8; j++) av[j] = (_Float16)vf[j];
      ah[m][kk] = av;
    }

  unsigned bv[2][4], b2[2][4];
#pragma unroll
  for (int m = 0; m < 2; m++)
#pragma unroll
    for (int r = 0; r < 4; r++) { bv[m][r] = 0xFFFFFFFFu; b2[m][r] = 0xFFFFFFFFu; }

#define MFMA_PHASE(BANK, KK)                                                   \
  {                                                                            \
    acc[0][0] = __builtin_amdgcn_mfma_f32_16x16x32_f16(ah[0][KK], BANK[KK][0], acc[0][0], 0, 0, 0); \
    acc[1][0] = __builtin_amdgcn_mfma_f32_16x16x32_f16(ah[1][KK], BANK[KK][0], acc[1][0], 0, 0, 0); \
    acc[0][1] = __builtin_amdgcn_mfma_f32_16x16x32_f16(ah[0][KK], BANK[KK][1], acc[0][1], 0, 0, 0); \
    acc[1][1] = __builtin_amdgcn_mfma_f32_16x16x32_f16(ah[1][KK], BANK[KK][1], acc[1][1], 0, 0, 0); \
  }

#define KEY_EPI(C)                                                             \
  {                                                                            \
    _Pragma("unroll")                                                          \
    for (int n = 0; n < 2; n++) {                                              \
      unsigned col = (unsigned)((C) * 32 + n * 16 + l15);                      \
      float e2v = n ? e2b : e2a;                                               \
      _Pragma("unroll")                                                        \
      for (int m = 0; m < 2; m++)                                              \
        _Pragma("unroll")                                                      \
        for (int r = 0; r < 4; r++) {                                          \
          float ks = fmaf(acc[m][n][r], -268435456.0f, e2v);                   \
          unsigned key = ((unsigned)ks & 0xFFFFFC00u) | col;                   \
          unsigned old = bv[m][r];                                             \
          bv[m][r] = min(old, key);                                            \
          b2[m][r] = min(b2[m][r], max(old, key));                             \
        }                                                                      \
    }                                                                          \
  }

  for (int c = 0; c < 32; c += 2) {
    // ---- chunk c from bank A; refill A with chunk c+2 behind each phase
    {
      float e2a = e2s[c * 32 + l15];
      float e2b = e2s[c * 32 + 16 + l15];
      f32x4 acc[2][2];
#pragma unroll
      for (int m = 0; m < 2; m++)
#pragma unroll
        for (int n = 0; n < 2; n++) acc[m][n] = (f32x4)(0.0f);
#pragma unroll
      for (int kk = 0; kk < 4; kk++) {
        MFMA_PHASE(FA, kk)
        if (c + 2 < 32) LOADG(FA[kk], c + 2, kk)
      }
      KEY_EPI(c)
    }
    // ---- chunk c+1 from bank B; refill B with chunk c+3
    {
      float e2a = e2s[(c + 1) * 32 + l15];
      float e2b = e2s[(c + 1) * 32 + 16 + l15];
      f32x4 acc[2][2];
#pragma unroll
      for (int m = 0; m < 2; m++)
#pragma unroll
        for (int n = 0; n < 2; n++) acc[m][n] = (f32x4)(0.0f);
#pragma unroll
      for (int kk = 0; kk < 4; kk++) {
        MFMA_PHASE(FB, kk)
        if (c + 3 < 32) LOADG(FB[kk], c + 3, kk)
      }
      KEY_EPI(c + 1)
    }
  }
#undef LOADG
#undef MFMA_PHASE
#undef KEY_EPI

  // reduce over the 16 column-lanes (u32 min keeps tie-break = smaller col)
#pragma unroll
  for (int m = 0; m < 2; m++)
#pragma unroll
    for (int r = 0; r < 4; r++) {
      unsigned v = bv[m][r], v2 = b2[m][r];
      for (int mask = 1; mask < 16; mask <<= 1) {
        unsigned ov = __shfl_xor(v, mask);
        unsigned o2 = __shfl_xor(v2, mask);
        v2 = min(min(v2, o2), max(v, ov));
        v  = min(v, ov);
      }
      if (l15 == 0) {
        int row = rbase + w * 32 + m * 16 + lo4 * 4 + r;
        int ii = (int)(v & 1023u);
        idx_arr[row] = ii;
        out_idx[row] = (float)ii;
        if ((v2 >> 10) - (v >> 10) < 79u) {   // gap < 6e-4 in score units
          int p = atomicAdd(nflag, 1); flags[p] = row;
        }
      }
    }
}

// ---- exact f64 recompute for near-tie rows (coalesced via embT) ----
__global__ __launch_bounds__(256)
void fb_k(const float* __restrict__ x, const float* __restrict__ embT,
          const double* __restrict__ en2d, const int* __restrict__ nflag,
          const int* __restrict__ flags, int* __restrict__ idx_arr,
          float* __restrict__ out_idx) {
  int n = *nflag;
  __shared__ double xsh[DIM];
  __shared__ double sv[256];
  __shared__ int    si[256];
  int t = threadIdx.x;
  for (int f = blockIdx.x; f < n; f += gridDim.x) {
    int row = flags[f];
    __syncthreads();
    if (t < DIM) xsh[t] = (double)x[row * DIM + t];
    __syncthreads();
    double xe0 = 0.0, xe1 = 0.0, xe2 = 0.0, xe3 = 0.0;
#pragma unroll 4
    for (int d = 0; d < DIM; d++) {
      float4 v = *(const float4*)&embT[d * NK + t * 4];
      double xd = xsh[d];
      xe0 = fma((double)v.x, xd, xe0);
      xe1 = fma((double)v.y, xd, xe1);
      xe2 = fma((double)v.z, xd, xe2);
      xe3 = fma((double)v.w, xd, xe3);
    }
    double s0 = en2d[t * 4 + 0] - 2.0 * xe0;
    double s1 = en2d[t * 4 + 1] - 2.0 * xe1;
    double s2 = en2d[t * 4 + 2] - 2.0 * xe2;
    double s3 = en2d[t * 4 + 3] - 2.0 * xe3;
    double bvv = s0; int bii = t * 4;
    if (s1 < bvv) { bvv = s1; bii = t * 4 + 1; }
    if (s2 < bvv) { bvv = s2; bii = t * 4 + 2; }
    if (s3 < bvv) { bvv = s3; bii = t * 4 + 3; }
    sv[t] = bvv; si[t] = bii;
    __syncthreads();
    for (int sh = 128; sh > 0; sh >>= 1) {
      if (t < sh) {
        double ov = sv[t + sh]; int oi = si[t + sh];
        if (ov < sv[t] || (ov == sv[t] && oi < si[t])) { sv[t] = ov; si[t] = oi; }
      }
      __syncthreads();
    }
    if (t == 0) { idx_arr[row] = si[0]; out_idx[row] = (float)si[0]; }
  }
}

// ---- per-block histogram (LDS bins, plain stores) ----
__global__ void histb_k(const int* __restrict__ idx, unsigned* __restrict__ bcount) {
  __shared__ unsigned bins[NK];
  int t = threadIdx.x;
  for (int b = t; b < NK; b += 256) bins[b] = 0u;
  __syncthreads();
#pragma unroll
  for (int j = 0; j < 4; j++)
    atomicAdd(&bins[idx[blockIdx.x * 1024 + j * 256 + t]], 1u);
  __syncthreads();
  for (int b = t; b < NK; b += 256) bcount[blockIdx.x * NK + b] = bins[b];
}

// ---- totals + scan + per-block starts + ncs/csk ----
__global__ void scan_k(unsigned* __restrict__ bcount, unsigned* __restrict__ icounts,
                       unsigned* __restrict__ offsets, const float* __restrict__ cs,
                       float* __restrict__ out_ncs, float* __restrict__ csk) {
  __shared__ unsigned sc[NK];
  __shared__ float sf[NK];
  int t = threadIdx.x;
  unsigned tot = 0;
#pragma unroll 8
  for (int b = 0; b < 64; b++) tot += bcount[b * NK + t];
  icounts[t] = tot;
  sc[t] = tot;
  __syncthreads();
  for (int off = 1; off < NK; off <<= 1) {
    unsigned v = (t >= off) ? sc[t - off] : 0u;
    __syncthreads();
    sc[t] += v;
    __syncthreads();
  }
  unsigned excl = sc[t] - tot;
  offsets[t] = excl;
  unsigned run = excl;
#pragma unroll 8
  for (int b = 0; b < 64; b++) {
    unsigned c = bcount[b * NK + t];
    bcount[b * NK + t] = run;          // becomes per-block start
    run += c;
  }
  float c0 = cs[t];
  float ncs = c0 * 0.99f + 0.01f * (float)tot;
  out_ncs[t] = ncs;
  sf[t] = c0;
  __syncthreads();
  for (int s = 512; s > 0; s >>= 1) {
    if (t < s) sf[t] += sf[t + s];
    __syncthreads();
  }
  float n = 0.99f * sf[0] + 655.36f;   // sum(ncs) = 0.99*sum(cs) + 0.01*65536
  csk[t] = (ncs + 1e-5f) / (n + 1024.0f * 1e-5f) * n;
}

// ---- scatter row ids (LDS cursors; no global atomics) ----
__global__ void scatter_k(const int* __restrict__ idx, const unsigned* __restrict__ bstart,
                          int* __restrict__ order) {
  __shared__ unsigned cur[NK];
  int t = threadIdx.x;
  for (int b = t; b < NK; b += 256) cur[b] = bstart[blockIdx.x * NK + b];
  __syncthreads();
#pragma unroll
  for (int j = 0; j < 4; j++) {
    int r = blockIdx.x * 1024 + j * 256 + t;
    unsigned p = atomicAdd(&cur[idx[r]], 1u);
    order[p] = r;
  }
}

// ---- fused gather: out_q, loss partials, dw_embed sums (no atomics) ----
__global__ __launch_bounds__(512)
void fgather_k(const float* __restrict__ x, const float* __restrict__ emb,
               const unsigned* __restrict__ offsets, const unsigned* __restrict__ icounts,
               const int* __restrict__ order, float* __restrict__ out_q,
               float* __restrict__ dwsum, float* __restrict__ partial) {
  int k = blockIdx.x, t = threadIdx.x;
  int d = t & 127, h = t >> 7;   // h = 0..3
  float e = emb[k * DIM + d];
  unsigned s = offsets[k], cnt = icounts[k];
  float acc = 0.f, ls = 0.f;
  for (unsigned j = h; j < cnt; j += 4) {
    int row = order[s + j];
    float xv = x[row * DIM + d];
    out_q[row * DIM + d] = e;
    acc += xv;
    float dd = e - xv;
    ls += dd * dd;
  }
  __shared__ float sa[512], sl[512];
  sa[t] = acc; sl[t] = ls;
  __syncthreads();
  if (t < 128) dwsum[k * DIM + t] = sa[t] + sa[t + 128] + sa[t + 256] + sa[t + 384];
  for (int sh = 256; sh > 0; sh >>= 1) {
    if (t < sh) sl[t] += sl[t + sh];
    __syncthreads();
  }
  if (t == 0) partial[k] = sl[0];
}

// ---- embed_avg EMA + new embedding; block 0 reduces loss ----
__global__ void emb_k(const float* __restrict__ embed_avg, const float* __restrict__ dwsum,
                      const float* __restrict__ csk, const float* __restrict__ partial,
                      float* __restrict__ out_nemb, float* __restrict__ out_nea,
                      float* __restrict__ out_loss) {
  if (blockIdx.x == 0) {
    __shared__ float red[256];
    int t = threadIdx.x;
    red[t] = partial[t] + partial[t + 256] + partial[t + 512] + partial[t + 768];
    __syncthreads();
    for (int sh = 128; sh > 0; sh >>= 1) {
      if (t < sh) red[t] += red[t + sh];
      __syncthreads();
    }
    if (t == 0) out_loss[0] = 2.0f * red[0] / 8388608.0f;
    return;
  }
  int i = (blockIdx.x - 1) * 256 + threadIdx.x;
  float na = embed_avg[i] * 0.99f + 0.01f * dwsum[i];
  out_nea[i] = na;
  out_nemb[i] = na / csk[i >> 7];
}

extern "C" void kernel_launch(void* const* d_in, const int* in_sizes, int n_in,
                              void* d_out, int out_size, void* d_ws, size_t ws_size,
                              hipStream_t stream) {
  const float* x   = (const float*)d_in[0];
  const float* emb = (const float*)d_in[1];
  const float* cs  = (const float*)d_in[2];
  const float* ea  = (const float*)d_in[3];

  float* out      = (float*)d_out;
  float* out_q    = out;                      // [65536,128]
  float* out_loss = out + 8388608;            // scalar
  float* out_idx  = out + 8388609;            // [65536]
  float* out_nemb = out + 8454145;            // [1024,128]
  float* out_ncs  = out + 8585217;            // [1024]
  float* out_nea  = out + 8586241;            // [1024,128]

  float* W        = (float*)d_ws;
  float* e2s      = W;                              // [0,1024)
  double* en2d    = (double*)(W + 1024);            // [1024,3072)
  char*  bpack    = (char*)(W + 3072);              // 256KB fp16 image
  float* dwsum    = W + 3072;                       // aliases bpack (dead after argmin)
  float* embT     = W + 134144;                     // [134144,265216) (dead after fb)
  unsigned* bcount = (unsigned*)(W + 134144);       // aliases embT lower (after fb)
  int*   order    = (int*)(W + 199680);             // aliases embT upper (after fb)
  float* partial  = W + 265216;                     // 1024
  unsigned* icounts = (unsigned*)(W + 266240);      // 1024
  unsigned* offsets = (unsigned*)(W + 267264);      // 1024
  float* csk      = W + 268288;                     // 1024
  int*   nflag    = (int*)(W + 269312);             // 1 (+pad)
  int*   flags    = (int*)(W + 269328);             // 65536
  int*   idx_arr  = (int*)(W + 334864);             // 65536

  bprep_k<<<64, 256, 0, stream>>>(emb, bpack, embT, e2s, en2d, nflag);
  argmin_k<<<1024, 128, 0, stream>>>(x, bpack, e2s, idx_arr, out_idx, nflag, flags);
  fb_k<<<1024, 256, 0, stream>>>(x, embT, en2d, nflag, flags, idx_arr, out_idx);
  histb_k<<<64, 256, 0, stream>>>(idx_arr, bcount);
  scan_k<<<1, 1024, 0, stream>>>(bcount, icounts, offsets, cs, out_ncs, csk);
  scatter_k<<<64, 256, 0, stream>>>(idx_arr, bcount, order);
  fgather_k<<<1024, 512, 0, stream>>>(x, emb, offsets, icounts, order, out_q, dwsum, partial);
  emb_k<<<513, 256, 0, stream>>>(ea, dwsum, csk, partial, out_nemb, out_nea, out_loss);
}

// Round 14
// 98.243 us; speedup vs baseline: 1.4784x; 1.1980x over previous
//
#include <hip/hip_runtime.h>

typedef __attribute__((ext_vector_type(8))) _Float16 half8;
typedef __attribute__((ext_vector_type(4))) float f32x4;

constexpr int NTOK = 65536;
constexpr int DIM  = 128;
constexpr int NK   = 1024;

// ---- prep: emb -> frag-major fp16 image for direct reg loads ----
// frag addr = chunk*8192 + kk*2048 + n*1024 + (lo4*16 + cl)*16
// + embT + f64 |e|^2 + scaled-key e2s; zeroes nflag.
__global__ void bprep_k(const float* __restrict__ emb, char* __restrict__ bp,
                        float* __restrict__ embT, float* __restrict__ e2s,
                        double* __restrict__ en2d, int* __restrict__ nflag) {
  int i = blockIdx.x * 256 + threadIdx.x;   // 0..16383
  if (i == 0) *nflag = 0;
  int c = i >> 4;          // code
  int g = i & 15;          // dim group (8 dims)
  float4 v0 = *(const float4*)&emb[c * 128 + g * 8];
  float4 v1 = *(const float4*)&emb[c * 128 + g * 8 + 4];
  float vf[8] = {v0.x, v0.y, v0.z, v0.w, v1.x, v1.y, v1.z, v1.w};
  half8 hv;
  double pacc = 0.0;
#pragma unroll
  for (int j = 0; j < 8; j++) {
    hv[j] = (_Float16)vf[j];
    embT[(g * 8 + j) * NK + c] = vf[j];
    pacc = fma((double)vf[j], (double)vf[j], pacc);
  }
  int chunk = c >> 5, n = (c >> 4) & 1, cl = c & 15;
  int kk = g >> 2, lo4 = g & 3;
  *(half8*)(bp + chunk * 8192 + kk * 2048 + n * 1024 + (lo4 * 16 + cl) * 16) = hv;
#pragma unroll
  for (int mask = 1; mask < 16; mask <<= 1) pacc += __shfl_xor(pacc, mask);
  if (g == 0) {
    en2d[c] = pacc;
    e2s[c] = (float)(pacc * 134217728.0 + 1073741824.0);  // e2*2^27 + 2^30
  }
}

// ---- main: fp16 MFMA distance + u32-key argmin ----
// 1024 blocks x 128 thr (2 waves). No LDS, no barriers: B-frags streamed
// global(L2)->reg via dual 4x2 register banks (2-chunk / 8-phase lookahead).
__global__ __launch_bounds__(128, 2)
void argmin_k(const float* __restrict__ x, const char* __restrict__ bp,
              const float* __restrict__ e2s, int* __restrict__ idx_arr,
              float* __restrict__ out_idx, int* __restrict__ nflag,
              int* __restrict__ flags) {
  const int t    = threadIdx.x;
  const int lane = t & 63;
  const int w    = t >> 6;              // 0..1
  const int l15  = lane & 15;
  const int lo4  = lane >> 4;
  const int rbase = blockIdx.x * 64;
  const int lb16 = lane * 16;

  half8 FA[4][2], FB[4][2];   // [kk][n]

#define LOADG(DST, C, KK)                                                      \
  {                                                                            \
    const char* _b = bp + ((C) * 8192 + (KK) * 2048) + lb16;                   \
    DST[0] = *(const half8*)_b;                                                \
    DST[1] = *(const half8*)(_b + 1024);                                       \
  }

  // prolog: chunks 0 and 1 fully in flight
#pragma unroll
  for (int kk = 0; kk < 4; kk++) LOADG(FA[kk], 0, kk)
#pragma unroll
  for (int kk = 0; kk < 4; kk++) LOADG(FB[kk], 1, kk)

  // A-frags (m=2): global -> regs, fp16 convert
  half8 ah[2][4];
#pragma unroll
  for (int m = 0; m < 2; m++)
#pragma unroll
    for (int kk = 0; kk < 4; kk++) {
      const float* xp = &x[(rbase + w * 32 + m * 16 + l15) * 128 + kk * 32 + lo4 * 8];
      float4 v0 = *(const float4*)xp;
      float4 v1 = *(const float4*)(xp + 4);
      float vf[8] = {v0.x, v0.y, v0.z, v0.w, v1.x, v1.y, v1.z, v1.w};
      half8 av;
#pragma unroll
      for (int j = 0; j < 8; j++) av[j] = (_Float16)vf[j];
      ah[m][kk] = av;
    }

  unsigned bv[2][4], b2[2][4];
#pragma unroll
  for (int m = 0; m < 2; m++)
#pragma unroll
    for (int r = 0; r < 4; r++) { bv[m][r] = 0xFFFFFFFFu; b2[m][r] = 0xFFFFFFFFu; }

#define MFMA_PHASE(BANK, KK)                                                   \
  {                                                                            \
    acc[0][0] = __builtin_amdgcn_mfma_f32_16x16x32_f16(ah[0][KK], BANK[KK][0], acc[0][0], 0, 0, 0); \
    acc[1][0] = __builtin_amdgcn_mfma_f32_16x16x32_f16(ah[1][KK], BANK[KK][0], acc[1][0], 0, 0, 0); \
    acc[0][1] = __builtin_amdgcn_mfma_f32_16x16x32_f16(ah[0][KK], BANK[KK][1], acc[0][1], 0, 0, 0); \
    acc[1][1] = __builtin_amdgcn_mfma_f32_16x16x32_f16(ah[1][KK], BANK[KK][1], acc[1][1], 0, 0, 0); \
  }

#define KEY_EPI(C)                                                             \
  {                                                                            \
    _Pragma("unroll")                                                          \
    for (int n = 0; n < 2; n++) {                                              \
      unsigned col = (unsigned)((C) * 32 + n * 16 + l15);                      \
      float e2v = n ? e2b : e2a;                                               \
      _Pragma("unroll")                                                        \
      for (int m = 0; m < 2; m++)                                              \
        _Pragma("unroll")                                                      \
        for (int r = 0; r < 4; r++) {                                          \
          float ks = fmaf(acc[m][n][r], -268435456.0f, e2v);                   \
          unsigned key = ((unsigned)ks & 0xFFFFFC00u) | col;                   \
          unsigned old = bv[m][r];                                             \
          bv[m][r] = min(old, key);                                            \
          b2[m][r] = min(b2[m][r], max(old, key));                             \
        }                                                                      \
    }                                                                          \
  }

  for (int c = 0; c < 32; c += 2) {
    {
      float e2a = e2s[c * 32 + l15];
      float e2b = e2s[c * 32 + 16 + l15];
      f32x4 acc[2][2];
#pragma unroll
      for (int m = 0; m < 2; m++)
#pragma unroll
        for (int n = 0; n < 2; n++) acc[m][n] = (f32x4)(0.0f);
#pragma unroll
      for (int kk = 0; kk < 4; kk++) {
        MFMA_PHASE(FA, kk)
        if (c + 2 < 32) LOADG(FA[kk], c + 2, kk)
      }
      KEY_EPI(c)
    }
    {
      float e2a = e2s[(c + 1) * 32 + l15];
      float e2b = e2s[(c + 1) * 32 + 16 + l15];
      f32x4 acc[2][2];
#pragma unroll
      for (int m = 0; m < 2; m++)
#pragma unroll
        for (int n = 0; n < 2; n++) acc[m][n] = (f32x4)(0.0f);
#pragma unroll
      for (int kk = 0; kk < 4; kk++) {
        MFMA_PHASE(FB, kk)
        if (c + 3 < 32) LOADG(FB[kk], c + 3, kk)
      }
      KEY_EPI(c + 1)
    }
  }
#undef LOADG
#undef MFMA_PHASE
#undef KEY_EPI

  // reduce over the 16 column-lanes (u32 min keeps tie-break = smaller col)
#pragma unroll
  for (int m = 0; m < 2; m++)
#pragma unroll
    for (int r = 0; r < 4; r++) {
      unsigned v = bv[m][r], v2 = b2[m][r];
      for (int mask = 1; mask < 16; mask <<= 1) {
        unsigned ov = __shfl_xor(v, mask);
        unsigned o2 = __shfl_xor(v2, mask);
        v2 = min(min(v2, o2), max(v, ov));
        v  = min(v, ov);
      }
      if (l15 == 0) {
        int row = rbase + w * 32 + m * 16 + lo4 * 4 + r;
        int ii = (int)(v & 1023u);
        idx_arr[row] = ii;
        out_idx[row] = (float)ii;
        if ((v2 >> 10) - (v >> 10) < 79u) {   // gap < 6e-4 in score units
          int p = atomicAdd(nflag, 1); flags[p] = row;
        }
      }
    }
}

// ---- exact f64 recompute for near-tie rows (coalesced via embT) ----
__global__ __launch_bounds__(256)
void fb_k(const float* __restrict__ x, const float* __restrict__ embT,
          const double* __restrict__ en2d, const int* __restrict__ nflag,
          const int* __restrict__ flags, int* __restrict__ idx_arr,
          float* __restrict__ out_idx) {
  int n = *nflag;
  __shared__ double xsh[DIM];
  __shared__ double sv[256];
  __shared__ int    si[256];
  int t = threadIdx.x;
  for (int f = blockIdx.x; f < n; f += gridDim.x) {
    int row = flags[f];
    __syncthreads();
    if (t < DIM) xsh[t] = (double)x[row * DIM + t];
    __syncthreads();
    double xe0 = 0.0, xe1 = 0.0, xe2 = 0.0, xe3 = 0.0;
#pragma unroll 4
    for (int d = 0; d < DIM; d++) {
      float4 v = *(const float4*)&embT[d * NK + t * 4];
      double xd = xsh[d];
      xe0 = fma((double)v.x, xd, xe0);
      xe1 = fma((double)v.y, xd, xe1);
      xe2 = fma((double)v.z, xd, xe2);
      xe3 = fma((double)v.w, xd, xe3);
    }
    double s0 = en2d[t * 4 + 0] - 2.0 * xe0;
    double s1 = en2d[t * 4 + 1] - 2.0 * xe1;
    double s2 = en2d[t * 4 + 2] - 2.0 * xe2;
    double s3 = en2d[t * 4 + 3] - 2.0 * xe3;
    double bvv = s0; int bii = t * 4;
    if (s1 < bvv) { bvv = s1; bii = t * 4 + 1; }
    if (s2 < bvv) { bvv = s2; bii = t * 4 + 2; }
    if (s3 < bvv) { bvv = s3; bii = t * 4 + 3; }
    sv[t] = bvv; si[t] = bii;
    __syncthreads();
    for (int sh = 128; sh > 0; sh >>= 1) {
      if (t < sh) {
        double ov = sv[t + sh]; int oi = si[t + sh];
        if (ov < sv[t] || (ov == sv[t] && oi < si[t])) { sv[t] = ov; si[t] = oi; }
      }
      __syncthreads();
    }
    if (t == 0) { idx_arr[row] = si[0]; out_idx[row] = (float)si[0]; }
  }
}

// ---- per-block histogram (LDS bins, plain stores) ----
__global__ void histb_k(const int* __restrict__ idx, unsigned* __restrict__ bcount) {
  __shared__ unsigned bins[NK];
  int t = threadIdx.x;
  for (int b = t; b < NK; b += 256) bins[b] = 0u;
  __syncthreads();
#pragma unroll
  for (int j = 0; j < 4; j++)
    atomicAdd(&bins[idx[blockIdx.x * 1024 + j * 256 + t]], 1u);
  __syncthreads();
  for (int b = t; b < NK; b += 256) bcount[blockIdx.x * NK + b] = bins[b];
}

// ---- totals + scan + per-block starts + ncs/csk ----
__global__ void scan_k(unsigned* __restrict__ bcount, unsigned* __restrict__ icounts,
                       unsigned* __restrict__ offsets, const float* __restrict__ cs,
                       float* __restrict__ out_ncs, float* __restrict__ csk) {
  __shared__ unsigned sc[NK];
  __shared__ float sf[NK];
  int t = threadIdx.x;
  unsigned tot = 0;
#pragma unroll 8
  for (int b = 0; b < 64; b++) tot += bcount[b * NK + t];
  icounts[t] = tot;
  sc[t] = tot;
  __syncthreads();
  for (int off = 1; off < NK; off <<= 1) {
    unsigned v = (t >= off) ? sc[t - off] : 0u;
    __syncthreads();
    sc[t] += v;
    __syncthreads();
  }
  unsigned excl = sc[t] - tot;
  offsets[t] = excl;
  unsigned run = excl;
#pragma unroll 8
  for (int b = 0; b < 64; b++) {
    unsigned c = bcount[b * NK + t];
    bcount[b * NK + t] = run;          // becomes per-block start
    run += c;
  }
  float c0 = cs[t];
  float ncs = c0 * 0.99f + 0.01f * (float)tot;
  out_ncs[t] = ncs;
  sf[t] = c0;
  __syncthreads();
  for (int s = 512; s > 0; s >>= 1) {
    if (t < s) sf[t] += sf[t + s];
    __syncthreads();
  }
  float n = 0.99f * sf[0] + 655.36f;   // sum(ncs) = 0.99*sum(cs) + 0.01*65536
  csk[t] = (ncs + 1e-5f) / (n + 1024.0f * 1e-5f) * n;
}

// ---- scatter row ids (LDS cursors; no global atomics) ----
__global__ void scatter_k(const int* __restrict__ idx, const unsigned* __restrict__ bstart,
                          int* __restrict__ order) {
  __shared__ unsigned cur[NK];
  int t = threadIdx.x;
  for (int b = t; b < NK; b += 256) cur[b] = bstart[blockIdx.x * NK + b];
  __syncthreads();
#pragma unroll
  for (int j = 0; j < 4; j++) {
    int r = blockIdx.x * 1024 + j * 256 + t;
    unsigned p = atomicAdd(&cur[idx[r]], 1u);
    order[p] = r;
  }
}

// ---- fused gather: out_q, loss partials, dw_embed half-sums ----
// 2048 blocks = 1024 codes x 2 halves; order-slice staged in LDS, unrolled loop.
__global__ __launch_bounds__(512)
void fgather_k(const float* __restrict__ x, const float* __restrict__ emb,
               const unsigned* __restrict__ offsets, const unsigned* __restrict__ icounts,
               const int* __restrict__ order, float* __restrict__ out_q,
               float* __restrict__ dwsum2, float* __restrict__ partial2) {
  __shared__ int ids[1024];
  int k = blockIdx.x >> 1, half = blockIdx.x & 1;
  int t = threadIdx.x;
  int d = t & 127, h = t >> 7;   // h = 0..3
  unsigned cnt = icounts[k];
  unsigned chl = cnt >> 1;
  unsigned s = offsets[k] + (half ? chl : 0u);
  unsigned myc = half ? (cnt - chl) : chl;
  for (unsigned j = t; j < myc && j < 1024u; j += 512) ids[j] = order[s + j];
  __syncthreads();
  float e = emb[k * DIM + d];
  float acc = 0.f, ls = 0.f;
#pragma unroll 4
  for (unsigned j = h; j < myc; j += 4) {
    int row = (j < 1024u) ? ids[j] : order[s + j];
    float xv = x[row * DIM + d];
    out_q[row * DIM + d] = e;
    acc += xv;
    float dd = e - xv;
    ls += dd * dd;
  }
  __shared__ float sa[512], sl[512];
  sa[t] = acc; sl[t] = ls;
  __syncthreads();
  if (t < 128) dwsum2[(half * NK + k) * DIM + t] = sa[t] + sa[t + 128] + sa[t + 256] + sa[t + 384];
  for (int sh = 256; sh > 0; sh >>= 1) {
    if (t < sh) sl[t] += sl[t + sh];
    __syncthreads();
  }
  if (t == 0) partial2[blockIdx.x] = sl[0];
}

// ---- embed_avg EMA + new embedding; block 0 reduces loss ----
__global__ void emb_k(const float* __restrict__ embed_avg, const float* __restrict__ dwsum2,
                      const float* __restrict__ csk, const float* __restrict__ partial2,
                      float* __restrict__ out_nemb, float* __restrict__ out_nea,
                      float* __restrict__ out_loss) {
  if (blockIdx.x == 0) {
    __shared__ float red[256];
    int t = threadIdx.x;
    float v = 0.f;
#pragma unroll
    for (int i = 0; i < 8; i++) v += partial2[t + 256 * i];
    red[t] = v;
    __syncthreads();
    for (int sh = 128; sh > 0; sh >>= 1) {
      if (t < sh) red[t] += red[t + sh];
      __syncthreads();
    }
    if (t == 0) out_loss[0] = 2.0f * red[0] / 8388608.0f;
    return;
  }
  int i = (blockIdx.x - 1) * 256 + threadIdx.x;
  float dw = dwsum2[i] + dwsum2[NK * DIM + i];
  float na = embed_avg[i] * 0.99f + 0.01f * dw;
  out_nea[i] = na;
  out_nemb[i] = na / csk[i >> 7];
}

extern "C" void kernel_launch(void* const* d_in, const int* in_sizes, int n_in,
                              void* d_out, int out_size, void* d_ws, size_t ws_size,
                              hipStream_t stream) {
  const float* x   = (const float*)d_in[0];
  const float* emb = (const float*)d_in[1];
  const float* cs  = (const float*)d_in[2];
  const float* ea  = (const float*)d_in[3];

  float* out      = (float*)d_out;
  float* out_q    = out;                      // [65536,128]
  float* out_loss = out + 8388608;            // scalar
  float* out_idx  = out + 8388609;            // [65536]
  float* out_nemb = out + 8454145;            // [1024,128]
  float* out_ncs  = out + 8585217;            // [1024]
  float* out_nea  = out + 8586241;            // [1024,128]

  float* W        = (float*)d_ws;
  float* e2s      = W;                              // [0,1024)
  double* en2d    = (double*)(W + 1024);            // [1024,3072)
  char*  bpack    = (char*)(W + 3072);              // 256KB fp16 image
  float* embT     = W + 134144;                     // [134144,265216) (dead after fb)
  unsigned* bcount = (unsigned*)(W + 134144);       // aliases embT lower (after fb)
  int*   order    = (int*)(W + 199680);             // aliases embT upper (after fb)
  unsigned* icounts = (unsigned*)(W + 266240);      // 1024
  unsigned* offsets = (unsigned*)(W + 267264);      // 1024
  float* csk      = W + 268288;                     // 1024
  int*   nflag    = (int*)(W + 269312);             // 1 (+pad)
  int*   flags    = (int*)(W + 269328);             // 65536
  int*   idx_arr  = (int*)(W + 334864);             // 65536
  float* dwsum2   = W + 400400;                     // 2*1024*128 = 262144
  float* partial2 = W + 662544;                     // 2048

  bprep_k<<<64, 256, 0, stream>>>(emb, bpack, embT, e2s, en2d, nflag);
  argmin_k<<<1024, 128, 0, stream>>>(x, bpack, e2s, idx_arr, out_idx, nflag, flags);
  fb_k<<<1024, 256, 0, stream>>>(x, embT, en2d, nflag, flags, idx_arr, out_idx);
  histb_k<<<64, 256, 0, stream>>>(idx_arr, bcount);
  scan_k<<<1, 1024, 0, stream>>>(bcount, icounts, offsets, cs, out_ncs, csk);
  scatter_k<<<64, 256, 0, stream>>>(idx_arr, bcount, order);
  fgather_k<<<2048, 512, 0, stream>>>(x, emb, offsets, icounts, order, out_q, dwsum2, partial2);
  emb_k<<<513, 256, 0, stream>>>(ea, dwsum2, csk, partial2, out_nemb, out_nea, out_loss);
}